// Round 12
// baseline (502.411 us; speedup 1.0000x reference)
//
#include <hip/hip_runtime.h>

// ---------------------------------------------------------------------------
// SiameseTripletModel: out = concat(anchor, pos, pos[argmin_j dist(i,j)])
//   anchor = anchor_x @ W + b ; pos = pos_x @ W + b   (all fp32 I/O)
//   dist[i,j] = |p_j|^2 - 2 a_i.p_j (+|a_i|^2 const), diag excluded, first-min.
//
// Round 20 (= round-19 BYTE-IDENTICAL RESUBMIT. Container died twice with no
// crash mechanism found in audit: protocol logic identical to r4/r7-proven
// rotation, vmcnt ladder checks, bounds check, 96KB < 128KB LDS cap.
// Precedent: round-8 "failed twice" -> round-9 identical resubmit RAN.
// If this fails twice again, enc-shaped dist is implicated -> revert to
// r7-proven 8-wave dist next round.)
//   * dist: enc-shaped A/B on the staging-rate anomaly (enc 6.4 TB/s vs
//     dist 3.2 TB/s staged): 256x128 tile, 256 thr / 4 waves (2Mx2N),
//     grid (32,16), 4 bufs (96KB), 6 gld16/thr, vmcnt(12/6/0), compiler
//     ds_reads, setprio. Staged 384MB; enc-rate -> ~60-75us, old -> ~115us.
//   * argmin_refine reads 32 partials (dist grid.x = 32).
//   * enc / split_all / fallback: byte-frozen vs round-18.
// ---------------------------------------------------------------------------

typedef short s8v __attribute__((ext_vector_type(8)));      // 8 bf16 (4 VGPRs)
typedef _Float16 h8v __attribute__((ext_vector_type(8)));   // 8 f16  (4 VGPRs)
typedef float f4v __attribute__((ext_vector_type(4)));      // MFMA accumulator
typedef unsigned short u16;

#define B  4096
#define D  1024
#define OLD 3072   // out leading dim (floats)
#define OLD16 6144 // out leading dim (u16)
#define LDK 68     // fallback-path LDS row (floats)

__device__ __forceinline__ u16 f2bf(float f) {
  union { float f; unsigned u; } v; v.f = f;
  unsigned r = v.u + 0x7FFFu + ((v.u >> 16) & 1u);  // RNE
  return (u16)(r >> 16);
}
__device__ __forceinline__ float bf2f(u16 s) {
  union { unsigned u; float f; } v; v.u = ((unsigned)s) << 16;
  return v.f;
}

// async 16B global->LDS (LDS dest wave-uniform; lane i lands at +16*i)
__device__ __forceinline__ void gld16(const void* g, void* l) {
  __builtin_amdgcn_global_load_lds(
      (const __attribute__((address_space(1))) unsigned int*)g,
      (__attribute__((address_space(3))) unsigned int*)l, 16, 0, 0);
}

// lexicographic top-2 / top-4 of (value, index); indices unique by construction
struct Top2 { float v1, v2; int j1, j2; };
__device__ __forceinline__ void t2_insert(Top2& t, float v, int j) {
  if (v < t.v1 || (v == t.v1 && j < t.j1)) {
    t.v2 = t.v1; t.j2 = t.j1; t.v1 = v; t.j1 = j;
  } else if (v < t.v2 || (v == t.v2 && j < t.j2)) {
    t.v2 = v; t.j2 = j;
  }
}
struct Top4 { float v[4]; int j[4]; };
__device__ __forceinline__ void t4_insert(Top4& t, float v, int j) {
  if (v < t.v[3] || (v == t.v[3] && j < t.j[3])) {
    int p = 3;
#pragma unroll
    for (int s = 0; s < 3; ++s) {
      if (p > 0 && (v < t.v[p - 1] || (v == t.v[p - 1] && j < t.j[p - 1]))) {
        t.v[p] = t.v[p - 1]; t.j[p] = t.j[p - 1]; --p;
      }
    }
    t.v[p] = v; t.j[p] = j;
  }
}

// ==== fused split: X hi/mid (anchor -> out dead third, pos -> posXq) +
//      W transpose hi/mid + p2 zeroing. One dispatch, block-range split. ====
__global__ __launch_bounds__(256) void split_all(
    const float* __restrict__ A, const float* __restrict__ P,
    const float* __restrict__ W, u16* __restrict__ O16,
    u16* __restrict__ posXq, u16* __restrict__ WtQ, float* __restrict__ p2) {
  __shared__ float tile[32][33];
  const int bb = blockIdx.x, tid = threadIdx.x;
  if (bb < 2 * B) {       // ---- splitX2 part ----
    const bool isPos = bb >= B;
    const int row = isPos ? bb - B : bb;
    const float4 v = *(const float4*)&(isPos ? P : A)[(size_t)row * D + tid * 4];
    const float vv[4] = {v.x, v.y, v.z, v.w};
    ushort4 hi, mi;
    u16* hp = &hi.x; u16* mp = &mi.x;
#pragma unroll
    for (int i = 0; i < 4; ++i) {
      hp[i] = f2bf(vv[i]);
      mp[i] = f2bf(vv[i] - bf2f(hp[i]));
    }
    if (isPos) {
      *(ushort4*)&posXq[(size_t)row * 2048 + tid * 4] = hi;
      *(ushort4*)&posXq[(size_t)row * 2048 + 1024 + tid * 4] = mi;
      if (tid == 0) p2[row] = 0.0f;   // re-poison-safe zero for fused norms
    } else {
      *(ushort4*)&O16[(size_t)row * OLD16 + 4096 + tid * 4] = hi;
      *(ushort4*)&O16[(size_t)row * OLD16 + 5120 + tid * 4] = mi;
    }
  } else {                // ---- splitT_W part ----
    const int b2 = bb - 2 * B;
    const int bx = (b2 & 31) * 32, by = (b2 >> 5) * 32;  // bx: n, by: k
    const int tx = tid & 31, ty = tid >> 5;              // 32 x 8
    for (int dy = 0; dy < 32; dy += 8)
      tile[ty + dy][tx] = W[(size_t)(by + ty + dy) * D + bx + tx];
    __syncthreads();
    for (int dy = 0; dy < 32; dy += 8) {
      const float v = tile[tx][ty + dy];     // k = by+tx, n = bx+ty+dy
      const u16 h = f2bf(v);
      const size_t o = (size_t)(bx + ty + dy) * 2048 + by + tx;
      WtQ[o] = h;
      WtQ[o + 1024] = f2bf(v - bf2f(h));
    }
  }
}

// ====== merged encoder MFMA GEMM (anchor + pos in one dispatch) =============
// XCD-aware remap (T1): XCD k gets A-panels {k,k+8,..} for all 8 N-blocks.
// 3 term-pairs hh+hm+mh (order preserved -> activations bit-stable).
// Depth-2 counted-vmcnt pipeline (T4): 4 k-step buffers x 32KB = 128KB LDS.
// Writes fp32 activations + f16 Aq/Pq + FUSED pos row-norms (atomicAdd p2).
__global__ __launch_bounds__(256) void enc_mfma(
    float* out, const u16* __restrict__ posXq, const u16* __restrict__ WtQ,
    const float* __restrict__ bias, _Float16* __restrict__ Aq,
    _Float16* __restrict__ Pq, float* __restrict__ p2) {
  __shared__ __align__(16) u16 lAh[4][128 * 32], lAm[4][128 * 32];  // 64 KB
  __shared__ __align__(16) u16 lBh[4][128 * 32], lBm[4][128 * 32];  // 64 KB
  const u16* O16 = (const u16*)out;
  const int tid = threadIdx.x, lane = tid & 63, wave = tid >> 6;
  const int waveM = wave >> 1, waveN = wave & 1;
  const int row16 = lane & 15, quad = lane >> 4;
  // bijective XCD swizzle: g = (by&7) | bx<<3 | (by>>3)<<6
  const int g = blockIdx.x + (blockIdx.y << 3);
  const int bx = (g >> 3) & 7;
  const int by = (g & 7) | ((g >> 6) << 3);
  const bool isPos = by >= 32;
  const int Mbase = (by & 31) * 128;
  const int Nbase = bx * 128;
  f4v acc[4][4] = {};
  const int slot = (quad ^ ((row16 >> 1) & 3)) * 8;   // read-side swizzle

  auto STAGE = [&](int buf, int kk) {
#pragma unroll
    for (int i = 0; i < 2; ++i) {
      const int c = i * 256 + tid;                  // 16B chunk id (0..511)
      const int row = c >> 2;
      const int col8 = ((c & 3) ^ ((row >> 1) & 3)) * 8;  // slot swizzle
      const int lo = (i * 256 + wave * 64) * 8;     // wave-uniform LDS base
      if (isPos) {
        gld16(&posXq[(size_t)(Mbase + row) * 2048 + kk + col8], &lAh[buf][lo]);
        gld16(&posXq[(size_t)(Mbase + row) * 2048 + 1024 + kk + col8], &lAm[buf][lo]);
      } else {
        gld16(&O16[(size_t)(Mbase + row) * OLD16 + 4096 + kk + col8], &lAh[buf][lo]);
        gld16(&O16[(size_t)(Mbase + row) * OLD16 + 5120 + kk + col8], &lAm[buf][lo]);
      }
      gld16(&WtQ[(size_t)(Nbase + row) * 2048 + kk + col8], &lBh[buf][lo]);
      gld16(&WtQ[(size_t)(Nbase + row) * 2048 + 1024 + kk + col8], &lBm[buf][lo]);
    }
  };

  STAGE(0, 0);          // 8 loads/thread in flight
  STAGE(1, 32);         // 16
  for (int t = 0; t < 32; ++t) {
    if (t + 2 < 32) STAGE((t + 2) & 3, (t + 2) * 32);   // 24 in flight
    if (t < 30)       asm volatile("s_waitcnt vmcnt(16)" ::: "memory");
    else if (t == 30) asm volatile("s_waitcnt vmcnt(8)" ::: "memory");
    else              asm volatile("s_waitcnt vmcnt(0)" ::: "memory");
    __builtin_amdgcn_sched_barrier(0);
    __builtin_amdgcn_s_barrier();
    __builtin_amdgcn_sched_barrier(0);
    const int cur = t & 3;
    s8v ah[4], am[4], bh[4], bm[4];
#pragma unroll
    for (int mi = 0; mi < 4; ++mi) {
      const int ro = (waveM * 64 + mi * 16 + row16) * 32 + slot;
      ah[mi] = *(const s8v*)&lAh[cur][ro];
      am[mi] = *(const s8v*)&lAm[cur][ro];
    }
#pragma unroll
    for (int ni = 0; ni < 4; ++ni) {
      const int ro = (waveN * 64 + ni * 16 + row16) * 32 + slot;
      bh[ni] = *(const s8v*)&lBh[cur][ro];
      bm[ni] = *(const s8v*)&lBm[cur][ro];
    }
    __builtin_amdgcn_s_setprio(1);
#pragma unroll
    for (int mi = 0; mi < 4; ++mi)
#pragma unroll
      for (int ni = 0; ni < 4; ++ni) {
        f4v a = acc[mi][ni];
        a = __builtin_amdgcn_mfma_f32_16x16x32_bf16(ah[mi], bh[ni], a, 0, 0, 0);
        a = __builtin_amdgcn_mfma_f32_16x16x32_bf16(ah[mi], bm[ni], a, 0, 0, 0);
        a = __builtin_amdgcn_mfma_f32_16x16x32_bf16(am[mi], bh[ni], a, 0, 0, 0);
        acc[mi][ni] = a;
      }
    __builtin_amdgcn_s_setprio(0);
  }
  // C/D layout: col = lane&15, row = quad*4 + r  [m89/m91 verified]
  const int outOff = isPos ? 1024 : 0;
  _Float16* Q = isPos ? Pq : Aq;
  float bv4[4];
#pragma unroll
  for (int ni = 0; ni < 4; ++ni)
    bv4[ni] = bias[Nbase + waveN * 64 + ni * 16 + row16];
#pragma unroll
  for (int mi = 0; mi < 4; ++mi) {
    const int rbase = Mbase + waveM * 64 + mi * 16 + quad * 4;
#pragma unroll
    for (int r = 0; r < 4; ++r) {
      const size_t row = rbase + r;
      float ss = 0.0f;
#pragma unroll
      for (int ni = 0; ni < 4; ++ni) {
        const int col = Nbase + waveN * 64 + ni * 16 + row16;
        const float v = acc[mi][ni][r] + bv4[ni];
        out[row * OLD + outOff + col] = v;
        Q[row * 1024 + col] = (_Float16)v;
        ss += v * v;
      }
      if (isPos) {  // fused pnorm: reduce over the 16 row16 lanes, 1 atomic
        ss += __shfl_xor(ss, 1, 64);
        ss += __shfl_xor(ss, 2, 64);
        ss += __shfl_xor(ss, 4, 64);
        ss += __shfl_xor(ss, 8, 64);
        if (row16 == 0) atomicAdd(&p2[row], ss);
      }
    }
  }
}

// ---------------- pos row norms (FALLBACK PATH ONLY) -------------------------
__global__ __launch_bounds__(256) void pnorm(float* __restrict__ o) {
  const int row = blockIdx.x, t = threadIdx.x;
  const float4 v = *(const float4*)&o[(size_t)row * OLD + D + t * 4];
  float s = v.x * v.x + v.y * v.y + v.z * v.z + v.w * v.w;
#pragma unroll
  for (int off = 32; off; off >>= 1) s += __shfl_down(s, off, 64);
  __shared__ float wsum[4];
  if ((t & 63) == 0) wsum[t >> 6] = s;
  __syncthreads();
  if (t == 0) o[(size_t)row * OLD + 2048] = wsum[0] + wsum[1] + wsum[2] + wsum[3];
}

// ====== dist MFMA (single f16 pair) + fused per-row TOP-2 ===================
// ENC-SHAPED (A/B on staging-rate hypothesis): 256x128 tile, 256 thr / 4
// waves (2Mx2N, per-wave acc[8][4]), grid (32,16) = 512 blocks, 4 k-step
// buffers (lA 64KB + lB 32KB = 96KB), 6 gld16/thread, vmcnt(12/6/0),
// compiler ds_reads, setprio. Same protocol as enc (proven).
// Aq/Pq: f16 [4096][1024]. part: float4 (v1,j1,v2,j2) per block (32/row).
__global__ __launch_bounds__(256) void dist_mfma(
    const _Float16* __restrict__ Aq, const _Float16* __restrict__ Pq,
    const float* __restrict__ p2, float* __restrict__ o) {
  __shared__ __align__(16) u16 lA[4][256 * 32];   // 64 KB
  __shared__ __align__(16) u16 lB[4][128 * 32];   // 32 KB
  const int tid = threadIdx.x, lane = tid & 63, wave = tid >> 6;  // 4 waves
  const int waveM = wave >> 1, waveN = wave & 1;   // 2M x 2N
  const int row16 = lane & 15, quad = lane >> 4;
  const int Mbase = blockIdx.y * 256;
  const int Nbase = blockIdx.x * 128;
  f4v acc[8][4] = {};
  const int slot = (quad ^ ((row16 >> 1) & 3)) * 8;   // read-side swizzle

  auto STAGE = [&](int buf, int kk) {
#pragma unroll
    for (int i = 0; i < 4; ++i) {                 // A: 1024 chunks (16 KB)
      const int c = i * 256 + tid;
      const int row = c >> 2;
      const int col8 = ((c & 3) ^ ((row >> 1) & 3)) * 8;  // slot swizzle
      gld16(&Aq[(size_t)(Mbase + row) * 1024 + kk + col8],
            &lA[buf][(i * 256 + wave * 64) * 8]);
    }
#pragma unroll
    for (int i = 0; i < 2; ++i) {                 // B: 512 chunks (8 KB)
      const int c = i * 256 + tid;
      const int row = c >> 2;
      const int col8 = ((c & 3) ^ ((row >> 1) & 3)) * 8;
      gld16(&Pq[(size_t)(Nbase + row) * 1024 + kk + col8],
            &lB[buf][(i * 256 + wave * 64) * 8]);
    }
  };

  STAGE(0, 0);          // 6 loads/thread in flight
  STAGE(1, 32);         // 12
  for (int t = 0; t < 32; ++t) {
    if (t + 2 < 32) STAGE((t + 2) & 3, (t + 2) * 32);   // 18 in flight
    // tile t's 6 loads retired; t+1/t+2 (12) stay in flight across barrier
    if (t < 30)       asm volatile("s_waitcnt vmcnt(12)" ::: "memory");
    else if (t == 30) asm volatile("s_waitcnt vmcnt(6)" ::: "memory");
    else              asm volatile("s_waitcnt vmcnt(0)" ::: "memory");
    __builtin_amdgcn_sched_barrier(0);
    __builtin_amdgcn_s_barrier();
    __builtin_amdgcn_sched_barrier(0);
    const int cur = t & 3;
    h8v a[8], b[4];
#pragma unroll
    for (int mi = 0; mi < 8; ++mi)
      a[mi] = *(const h8v*)&lA[cur][(waveM * 128 + mi * 16 + row16) * 32 + slot];
#pragma unroll
    for (int ni = 0; ni < 4; ++ni)
      b[ni] = *(const h8v*)&lB[cur][(waveN * 64 + ni * 16 + row16) * 32 + slot];
    __builtin_amdgcn_s_setprio(1);
#pragma unroll
    for (int mi = 0; mi < 8; ++mi)
#pragma unroll
      for (int ni = 0; ni < 4; ++ni)
        acc[mi][ni] =
            __builtin_amdgcn_mfma_f32_16x16x32_f16(a[mi], b[ni], acc[mi][ni], 0, 0, 0);
    __builtin_amdgcn_s_setprio(0);
    // buffer rotation: epoch-t readers use buf t&3; in-flight DMA targets
    // (t+1)&3/(t+2)&3; next stage-issue targets (t+3)&3 (its prior readers
    // finished before the barrier above). All distinct with 4 buffers.
  }
  __syncthreads();   // drained; reuse lA[0] for reduction arrays

  float (*sv1)[2] = (float(*)[2])&lA[0][0];            // 2 KB
  float (*sv2)[2] = (float(*)[2])((char*)&lA[0][0] + 2048);
  int   (*sj1)[2] = (int(*)[2])((char*)&lA[0][0] + 4096);
  int   (*sj2)[2] = (int(*)[2])((char*)&lA[0][0] + 6144);

  // epilogue: d = p2[col] - 2*S; per-row TOP-2 across this block's 128 cols.
  float p2c[4];
#pragma unroll
  for (int ni = 0; ni < 4; ++ni)
    p2c[ni] = p2[Nbase + waveN * 64 + ni * 16 + row16];
#pragma unroll
  for (int mi = 0; mi < 8; ++mi)
#pragma unroll
    for (int r = 0; r < 4; ++r) {
      const int rg = Mbase + waveM * 128 + mi * 16 + quad * 4 + r;
      Top2 tp; tp.v1 = 3.0e38f; tp.v2 = 3.0e38f; tp.j1 = 0; tp.j2 = 1;
#pragma unroll
      for (int ni = 0; ni < 4; ++ni) {
        const int cg = Nbase + waveN * 64 + ni * 16 + row16;
        if (cg != rg) t2_insert(tp, p2c[ni] - 2.0f * acc[mi][ni][r], cg);
      }
#pragma unroll
      for (int m = 1; m < 16; m <<= 1) {  // across the 16 row16 lanes
        const float ov1 = __shfl_xor(tp.v1, m, 64);
        const int oj1 = __shfl_xor(tp.j1, m, 64);
        const float ov2 = __shfl_xor(tp.v2, m, 64);
        const int oj2 = __shfl_xor(tp.j2, m, 64);
        t2_insert(tp, ov1, oj1);
        t2_insert(tp, ov2, oj2);
      }
      if (row16 == 0) {
        const int rl = waveM * 128 + mi * 16 + quad * 4 + r;
        sv1[rl][waveN] = tp.v1; sj1[rl][waveN] = tp.j1;
        sv2[rl][waveN] = tp.v2; sj2[rl][waveN] = tp.j2;
      }
    }
  __syncthreads();
  {
    Top2 tp; tp.v1 = sv1[tid][0]; tp.j1 = sj1[tid][0];
    tp.v2 = sv2[tid][0]; tp.j2 = sj2[tid][0];
    t2_insert(tp, sv1[tid][1], sj1[tid][1]);
    t2_insert(tp, sv2[tid][1], sj2[tid][1]);
    ((float4*)&o[(size_t)(Mbase + tid) * OLD + 2056])[blockIdx.x] =
        make_float4(tp.v1, __int_as_float(tp.j1), tp.v2, __int_as_float(tp.j2));
  }
}

// ===== final: global TOP-4, EXACT fp32 refine, gather neg row ================
__global__ __launch_bounds__(256) void argmin_refine(float* __restrict__ o) {
  const int i = blockIdx.x, t = threadIdx.x;
  __shared__ int gj[4];
  if (t < 64) {
    Top4 tp;
#pragma unroll
    for (int c = 0; c < 4; ++c) { tp.v[c] = 3.0e38f; tp.j[c] = 0; }
    if (t < 32) {   // 32 partial blocks (dist grid.x = 32)
      const float4 p = ((const float4*)&o[(size_t)i * OLD + 2056])[t];
      t4_insert(tp, p.x, __float_as_int(p.y));
      t4_insert(tp, p.z, __float_as_int(p.w));
    }
#pragma unroll
    for (int m = 1; m < 32; m <<= 1) {
#pragma unroll
      for (int c = 0; c < 4; ++c) {
        const float ov = __shfl_xor(tp.v[c], m, 64);
        const int oj = __shfl_xor(tp.j[c], m, 64);
        t4_insert(tp, ov, oj);
      }
    }
    if (t == 0) {
#pragma unroll
      for (int c = 0; c < 4; ++c)
        gj[c] = (tp.j[c] < 0) ? 0 : (tp.j[c] > B - 1 ? B - 1 : tp.j[c]);  // clamp
    }
  }
  __syncthreads();
  int jj[4];
#pragma unroll
  for (int c = 0; c < 4; ++c) jj[c] = gj[c];
  // exact fp32: d_c = |p_jc|^2 - 2 a_i.p_jc (norms recomputed locally)
  const float4 a4 = *(const float4*)&o[(size_t)i * OLD + t * 4];
  float s[4], n[4];
#pragma unroll
  for (int c = 0; c < 4; ++c) {
    const float4 q = *(const float4*)&o[(size_t)jj[c] * OLD + D + t * 4];
    s[c] = a4.x * q.x + a4.y * q.y + a4.z * q.z + a4.w * q.w;
    n[c] = q.x * q.x + q.y * q.y + q.z * q.z + q.w * q.w;
  }
#pragma unroll
  for (int off = 32; off; off >>= 1)
#pragma unroll
    for (int c = 0; c < 4; ++c) {
      s[c] += __shfl_down(s[c], off, 64);
      n[c] += __shfl_down(n[c], off, 64);
    }
  __shared__ float wsum[4][8];
  __shared__ int sjf;
  if ((t & 63) == 0)
#pragma unroll
    for (int c = 0; c < 4; ++c) {
      wsum[t >> 6][c] = s[c];
      wsum[t >> 6][4 + c] = n[c];
    }
  __syncthreads();
  if (t == 0) {
    float bd = 3.4e38f; int bj = 0x7fffffff;
#pragma unroll
    for (int c = 0; c < 4; ++c) {
      const float S = wsum[0][c] + wsum[1][c] + wsum[2][c] + wsum[3][c];
      const float N = wsum[0][4 + c] + wsum[1][4 + c] + wsum[2][4 + c] + wsum[3][4 + c];
      const float d = N - 2.0f * S;
      const int j = jj[c];
      if (d < bd || (d == bd && j < bj)) { bd = d; bj = j; }
    }
    sjf = bj;
  }
  __syncthreads();
  const int j = sjf;
  ((float4*)&o[(size_t)i * OLD + 2048])[t] = ((const float4*)&o[(size_t)j * OLD + D])[t];
}

// ================== round-4 fallback path (fp32 vector, ws-free) =============
__global__ __launch_bounds__(256) void enc_gemm(
    const float* __restrict__ X, const float* __restrict__ W,
    const float* __restrict__ bia, float* __restrict__ out, int outOff) {
  __shared__ float lA[32][LDK];
  __shared__ float lW[32][LDK];
  const int tid = threadIdx.x;
  const int Mbase = blockIdx.y * 64;
  const int Nbase = blockIdx.x * 64;
  const int ty = tid >> 4, tx = tid & 15;
  float acc[4][4] = {};
  for (int k0 = 0; k0 < D; k0 += 32) {
    __syncthreads();
#pragma unroll
    for (int h = 0; h < 2; ++h) {
      const int ch = tid + h * 256;
      const int r = ch >> 3, c4 = (ch & 7) * 4;
      const float4 a4 = *(const float4*)&X[(size_t)(Mbase + r) * D + k0 + c4];
      lA[c4 + 0][r] = a4.x; lA[c4 + 1][r] = a4.y;
      lA[c4 + 2][r] = a4.z; lA[c4 + 3][r] = a4.w;
      const int kr = ch >> 4, nc = (ch & 15) * 4;
      *(float4*)&lW[kr][nc] = *(const float4*)&W[(size_t)(k0 + kr) * D + Nbase + nc];
    }
    __syncthreads();
#pragma unroll
    for (int kk = 0; kk < 32; ++kk) {
      const float4 av = *(const float4*)&lA[kk][ty * 4];
      const float4 wv = *(const float4*)&lW[kk][tx * 4];
      acc[0][0] += av.x * wv.x; acc[0][1] += av.x * wv.y; acc[0][2] += av.x * wv.z; acc[0][3] += av.x * wv.w;
      acc[1][0] += av.y * wv.x; acc[1][1] += av.y * wv.y; acc[1][2] += av.y * wv.z; acc[1][3] += av.y * wv.w;
      acc[2][0] += av.z * wv.x; acc[2][1] += av.z * wv.y; acc[2][2] += av.z * wv.z; acc[2][3] += av.z * wv.w;
      acc[3][0] += av.w * wv.x; acc[3][1] += av.w * wv.y; acc[3][2] += av.w * wv.z; acc[3][3] += av.w * wv.w;
    }
  }
  const float4 b4 = *(const float4*)&bia[Nbase + tx * 4];
#pragma unroll
  for (int i = 0; i < 4; ++i) {
    const int row = Mbase + ty * 4 + i;
    float4 ov;
    ov.x = acc[i][0] + b4.x; ov.y = acc[i][1] + b4.y;
    ov.z = acc[i][2] + b4.z; ov.w = acc[i][3] + b4.w;
    *(float4*)&out[(size_t)row * OLD + outOff + Nbase + tx * 4] = ov;
  }
}

__global__ __launch_bounds__(256) void dist_argmin_f32(float* __restrict__ o) {
  __shared__ float lA[32][LDK];
  __shared__ float lB[32][LDK];
  const int tid = threadIdx.x;
  const int Mbase = blockIdx.y * 64, Nbase = blockIdx.x * 64;
  const int ty = tid >> 4, tx = tid & 15;
  float acc[4][4] = {};
  for (int k0 = 0; k0 < D; k0 += 32) {
    __syncthreads();
#pragma unroll
    for (int h = 0; h < 2; ++h) {
      const int ch = tid + h * 256;
      const int r = ch >> 3, c4 = (ch & 7) * 4;
      const float4 a4 = *(const float4*)&o[(size_t)(Mbase + r) * OLD + k0 + c4];
      const float4 b4 = *(const float4*)&o[(size_t)(Nbase + r) * OLD + D + k0 + c4];
      lA[c4 + 0][r] = a4.x; lA[c4 + 1][r] = a4.y;
      lA[c4 + 2][r] = a4.z; lA[c4 + 3][r] = a4.w;
      lB[c4 + 0][r] = b4.x; lB[c4 + 1][r] = b4.y;
      lB[c4 + 2][r] = b4.z; lB[c4 + 3][r] = b4.w;
    }
    __syncthreads();
#pragma unroll
    for (int kk = 0; kk < 32; ++kk) {
      const float4 av = *(const float4*)&lA[kk][ty * 4];
      const float4 bv = *(const float4*)&lB[kk][tx * 4];
      acc[0][0] += av.x * bv.x; acc[0][1] += av.x * bv.y; acc[0][2] += av.x * bv.z; acc[0][3] += av.x * bv.w;
      acc[1][0] += av.y * bv.x; acc[1][1] += av.y * bv.y; acc[1][2] += av.y * bv.z; acc[1][3] += av.y * bv.w;
      acc[2][0] += av.z * bv.x; acc[2][1] += av.z * bv.y; acc[2][2] += av.z * bv.z; acc[2][3] += av.z * bv.w;
      acc[3][0] += av.w * bv.x; acc[3][1] += av.w * bv.y; acc[3][2] += av.w * bv.z; acc[3][3] += av.w * bv.w;
    }
  }
  float colp2[4];
#pragma unroll
  for (int j = 0; j < 4; ++j)
    colp2[j] = o[(size_t)(Nbase + tx * 4 + j) * OLD + 2048];
#pragma unroll
  for (int i = 0; i < 4; ++i) {
    const int rg = Mbase + ty * 4 + i;
    float bv = 3.0e38f; int bj = 0;
#pragma unroll
    for (int j = 0; j < 4; ++j) {
      const int cg = Nbase + tx * 4 + j;
      const float d = colp2[j] - 2.0f * acc[i][j];
      if (cg != rg && d < bv) { bv = d; bj = cg; }
    }
#pragma unroll
    for (int m = 1; m < 16; m <<= 1) {
      const float ov = __shfl_xor(bv, m, 64);
      const int oj = __shfl_xor(bj, m, 64);
      if (ov < bv || (ov == bv && oj < bj)) { bv = ov; bj = oj; }
    }
    if (tx == 0)
      ((float2*)&o[(size_t)rg * OLD + 2056])[blockIdx.x] =
          make_float2(bv, __int_as_float(bj));
  }
}

__global__ __launch_bounds__(256) void argmin_final_f2(float* __restrict__ o, int nblk) {
  const int i = blockIdx.x, t = threadIdx.x;
  __shared__ int sj;
  if (t < 64) {
    float v = 3.4e38f; int j = 0x7fffffff;
    if (t < nblk) {
      const float2 p = ((const float2*)&o[(size_t)i * OLD + 2056])[t];
      v = p.x; j = __float_as_int(p.y);
    }
#pragma unroll
    for (int m = 32; m; m >>= 1) {
      const float ov = __shfl_xor(v, m, 64);
      const int oj = __shfl_xor(j, m, 64);
      if (ov < v || (ov == v && oj < j)) { v = ov; j = oj; }
    }
    if (t == 0) sj = (j < 0) ? 0 : (j > B - 1 ? B - 1 : j);
  }
  __syncthreads();
  const int j = sj;
  ((float4*)&o[(size_t)i * OLD + 2048])[t] = ((const float4*)&o[(size_t)j * OLD + D])[t];
}

extern "C" void kernel_launch(void* const* d_in, const int* in_sizes, int n_in,
                              void* d_out, int out_size, void* d_ws, size_t ws_size,
                              hipStream_t stream) {
  const float* anchor_x = (const float*)d_in[0];  // [4096,1024] f32
  const float* pos_x    = (const float*)d_in[1];  // [4096,1024] f32
  const float* W        = (const float*)d_in[2];  // [1024,1024] f32
  const float* b        = (const float*)d_in[3];  // [1024] f32
  float* out = (float*)d_out;                     // [4096,3072] f32
  char* ws = (char*)d_ws;
  const size_t MB = 1024 * 1024;

  if (ws_size >= 37 * MB) {  // fast path needs 36MB + 16KB
    _Float16* Aq = (_Float16*)(ws);            // [4096][1024] f16, 8 MB
    _Float16* Pq = (_Float16*)(ws + 8 * MB);   // 8 MB
    u16* WtQ     = (u16*)(ws + 16 * MB);       // [1024][2048] bf16 hi|mid, 4 MB
    u16* posXq   = (u16*)(ws + 20 * MB);       // [4096][2048] bf16 hi|mid, 16 MB
    float* p2    = (float*)(ws + 36 * MB);     // [4096] f32 pos row norms
    split_all<<<2 * B + 1024, 256, 0, stream>>>(anchor_x, pos_x, W,
                                                (u16*)out, posXq, WtQ, p2);
    enc_mfma<<<dim3(8, 64), 256, 0, stream>>>(out, posXq, WtQ, b, Aq, Pq, p2);
    dist_mfma<<<dim3(32, 16), 256, 0, stream>>>(Aq, Pq, p2, out);
    argmin_refine<<<B, 256, 0, stream>>>(out);
  } else {  // round-4 proven path: d_ws untouched
    enc_gemm<<<dim3(16, 64), 256, 0, stream>>>(anchor_x, W, b, out, 0);
    enc_gemm<<<dim3(16, 64), 256, 0, stream>>>(pos_x,    W, b, out, 1024);
    pnorm<<<B, 256, 0, stream>>>(out);
    dist_argmin_f32<<<dim3(64, 64), 256, 0, stream>>>(out);
    argmin_final_f2<<<B, 256, 0, stream>>>(out, 64);
  }
}

// Round 13
// 286.664 us; speedup vs baseline: 1.7526x; 1.7526x over previous
//
#include <hip/hip_runtime.h>

// ---------------------------------------------------------------------------
// SiameseTripletModel: out = concat(anchor, pos, pos[argmin_j dist(i,j)])
//   anchor = anchor_x @ W + b ; pos = pos_x @ W + b   (all fp32 I/O)
//   dist[i,j] = |p_j|^2 - 2 a_i.p_j (+|a_i|^2 const), diag excluded, first-min.
//
// FINAL (round 21 = round-10/r2 best-measured config, byte-identical replay):
//   12 rounds of data: six passing variants (dbuf/4-buf counted-vmcnt
//   pipelines, T1 XCD swizzle, dispatch fusion 6->4, f16/bf16 trades) all
//   land at 287-299us; per-dispatch sums ~190us vs dur_us ~290 -> fixed
//   ~100us overhead invariant to kernel changes. This config measured the
//   session best: 287.45us, absmax 0.015625 (baseline was 336.3).
//   * enc: 128^2 tile, single-buffer 2-barrier bf16 3-pair (hh+hm+mh) loop,
//     XOR chunk swizzle (bank-conflict-free), f16 Aq/Pq epilogue.
//   * dist: 256x256 tile, 8 waves, f16 single-pair MFMA, double-buffered
//     LDS 1-barrier/K-step, XOR swizzle; per-block TOP-2 partials.
//   * argmin_refine: global TOP-4 + EXACT fp32 refine + neg-row gather.
//   * round-4 fp32 vector path kept as fallback for ws < 36 MB.
// ---------------------------------------------------------------------------

typedef short s8v __attribute__((ext_vector_type(8)));      // 8 bf16 (4 VGPRs)
typedef _Float16 h8v __attribute__((ext_vector_type(8)));   // 8 f16  (4 VGPRs)
typedef float f4v __attribute__((ext_vector_type(4)));      // MFMA accumulator
typedef unsigned short u16;

#define B  4096
#define D  1024
#define OLD 3072   // out leading dim (floats)
#define OLD16 6144 // out leading dim (u16)
#define LDK 68     // fallback-path LDS row (floats)

__device__ __forceinline__ u16 f2bf(float f) {
  union { float f; unsigned u; } v; v.f = f;
  unsigned r = v.u + 0x7FFFu + ((v.u >> 16) & 1u);  // RNE
  return (u16)(r >> 16);
}
__device__ __forceinline__ float bf2f(u16 s) {
  union { unsigned u; float f; } v; v.u = ((unsigned)s) << 16;
  return v.f;
}

// async 16B global->LDS (LDS dest wave-uniform; lane i lands at +16*i)
__device__ __forceinline__ void gld16(const void* g, void* l) {
  __builtin_amdgcn_global_load_lds(
      (const __attribute__((address_space(1))) unsigned int*)g,
      (__attribute__((address_space(3))) unsigned int*)l, 16, 0, 0);
}

// lexicographic top-2 / top-4 of (value, index); indices unique by construction
struct Top2 { float v1, v2; int j1, j2; };
__device__ __forceinline__ void t2_insert(Top2& t, float v, int j) {
  if (v < t.v1 || (v == t.v1 && j < t.j1)) {
    t.v2 = t.v1; t.j2 = t.j1; t.v1 = v; t.j1 = j;
  } else if (v < t.v2 || (v == t.v2 && j < t.j2)) {
    t.v2 = v; t.j2 = j;
  }
}
struct Top4 { float v[4]; int j[4]; };
__device__ __forceinline__ void t4_insert(Top4& t, float v, int j) {
  if (v < t.v[3] || (v == t.v[3] && j < t.j[3])) {
    int p = 3;
#pragma unroll
    for (int s = 0; s < 3; ++s) {
      if (p > 0 && (v < t.v[p - 1] || (v == t.v[p - 1] && j < t.j[p - 1]))) {
        t.v[p] = t.v[p - 1]; t.j[p] = t.j[p - 1]; --p;
      }
    }
    t.v[p] = v; t.j[p] = j;
  }
}

// ================= W transpose + 2-way split: WtQ[n][hi k | mid k] ===========
__global__ void splitT_W(const float* __restrict__ W, u16* __restrict__ WtQ) {
  __shared__ float tile[32][33];
  const int bx = blockIdx.x * 32, by = blockIdx.y * 32;  // bx: n, by: k
  const int tx = threadIdx.x, ty = threadIdx.y;
  for (int dy = 0; dy < 32; dy += 8)
    tile[ty + dy][tx] = W[(size_t)(by + ty + dy) * D + bx + tx];
  __syncthreads();
  for (int dy = 0; dy < 32; dy += 8) {
    const float v = tile[tx][ty + dy];       // k = by+tx, n = bx+ty+dy
    const u16 h = f2bf(v);
    const size_t o = (size_t)(bx + ty + dy) * 2048 + by + tx;
    WtQ[o] = h;
    WtQ[o + 1024] = f2bf(v - bf2f(h));
  }
}

// ==== X split to bf16 hi/mid: anchor -> out dead third, pos -> posXq (ws) ====
__global__ __launch_bounds__(256) void splitX2(
    const float* __restrict__ A, const float* __restrict__ P,
    u16* __restrict__ O16, u16* __restrict__ posXq) {
  const int r = blockIdx.x, t = threadIdx.x;
  const bool isPos = r >= B;
  const int row = isPos ? r - B : r;
  const float4 v = *(const float4*)&(isPos ? P : A)[(size_t)row * D + t * 4];
  const float vv[4] = {v.x, v.y, v.z, v.w};
  ushort4 hi, mi;
  u16* hp = &hi.x; u16* mp = &mi.x;
#pragma unroll
  for (int i = 0; i < 4; ++i) {
    hp[i] = f2bf(vv[i]);
    mp[i] = f2bf(vv[i] - bf2f(hp[i]));
  }
  if (isPos) {
    *(ushort4*)&posXq[(size_t)row * 2048 + t * 4] = hi;
    *(ushort4*)&posXq[(size_t)row * 2048 + 1024 + t * 4] = mi;
  } else {
    *(ushort4*)&O16[(size_t)row * OLD16 + 4096 + t * 4] = hi;
    *(ushort4*)&O16[(size_t)row * OLD16 + 5120 + t * 4] = mi;
  }
}

// ====== merged encoder MFMA GEMM (anchor + pos in one dispatch) =============
// blockIdx.y < 32: anchor rows (A from out dead third); else pos (from posXq).
// 3 term-pairs hh+hm+mh (order preserved -> activations bit-stable).
// Single-buffer 2-barrier loop + XOR chunk swizzle.
// Writes fp32 activations + single-f16 Aq/Pq.
__global__ __launch_bounds__(256) void enc_mfma(
    float* out, const u16* __restrict__ posXq, const u16* __restrict__ WtQ,
    const float* __restrict__ bias, _Float16* __restrict__ Aq,
    _Float16* __restrict__ Pq) {
  __shared__ __align__(16) u16 lAh[128 * 32], lAm[128 * 32];
  __shared__ __align__(16) u16 lBh[128 * 32], lBm[128 * 32];
  const u16* O16 = (const u16*)out;
  const int tid = threadIdx.x, lane = tid & 63, wave = tid >> 6;
  const int waveM = wave >> 1, waveN = wave & 1;
  const int row16 = lane & 15, quad = lane >> 4;
  const bool isPos = blockIdx.y >= 32;
  const int Mbase = (blockIdx.y & 31) * 128;
  const int Nbase = blockIdx.x * 128;   // 8 blocks
  f4v acc[4][4] = {};
  const int slot = (quad ^ ((row16 >> 1) & 3)) * 8;   // read-side swizzle

  for (int kk = 0; kk < D; kk += 32) {
    __syncthreads();
#pragma unroll
    for (int i = 0; i < 2; ++i) {
      const int c = i * 256 + tid;                  // 16B chunk id (0..511)
      const int row = c >> 2;
      const int col8 = ((c & 3) ^ ((row >> 1) & 3)) * 8;  // slot swizzle
      const int lo = (i * 256 + wave * 64) * 8;     // wave-uniform LDS base
      if (isPos) {
        gld16(&posXq[(size_t)(Mbase + row) * 2048 + kk + col8], &lAh[lo]);
        gld16(&posXq[(size_t)(Mbase + row) * 2048 + 1024 + kk + col8], &lAm[lo]);
      } else {
        gld16(&O16[(size_t)(Mbase + row) * OLD16 + 4096 + kk + col8], &lAh[lo]);
        gld16(&O16[(size_t)(Mbase + row) * OLD16 + 5120 + kk + col8], &lAm[lo]);
      }
      gld16(&WtQ[(size_t)(Nbase + row) * 2048 + kk + col8], &lBh[lo]);
      gld16(&WtQ[(size_t)(Nbase + row) * 2048 + 1024 + kk + col8], &lBm[lo]);
    }
    __syncthreads();
    s8v ah[4], am[4], bh[4], bm[4];
#pragma unroll
    for (int mi = 0; mi < 4; ++mi) {
      const int ro = (waveM * 64 + mi * 16 + row16) * 32 + slot;
      ah[mi] = *(const s8v*)&lAh[ro];
      am[mi] = *(const s8v*)&lAm[ro];
    }
#pragma unroll
    for (int ni = 0; ni < 4; ++ni) {
      const int ro = (waveN * 64 + ni * 16 + row16) * 32 + slot;
      bh[ni] = *(const s8v*)&lBh[ro];
      bm[ni] = *(const s8v*)&lBm[ro];
    }
#pragma unroll
    for (int mi = 0; mi < 4; ++mi)
#pragma unroll
      for (int ni = 0; ni < 4; ++ni) {
        f4v a = acc[mi][ni];
        a = __builtin_amdgcn_mfma_f32_16x16x32_bf16(ah[mi], bh[ni], a, 0, 0, 0);
        a = __builtin_amdgcn_mfma_f32_16x16x32_bf16(ah[mi], bm[ni], a, 0, 0, 0);
        a = __builtin_amdgcn_mfma_f32_16x16x32_bf16(am[mi], bh[ni], a, 0, 0, 0);
        acc[mi][ni] = a;
      }
  }
  // C/D layout: col = lane&15, row = quad*4 + r  [m89/m91 verified]
  const int outOff = isPos ? 1024 : 0;
  _Float16* Q = isPos ? Pq : Aq;
#pragma unroll
  for (int ni = 0; ni < 4; ++ni) {
    const int col = Nbase + waveN * 64 + ni * 16 + row16;
    const float bv = bias[col];
#pragma unroll
    for (int mi = 0; mi < 4; ++mi) {
      const int rbase = Mbase + waveM * 64 + mi * 16 + quad * 4;
#pragma unroll
      for (int r = 0; r < 4; ++r) {
        const size_t row = rbase + r;
        const float v = acc[mi][ni][r] + bv;
        out[row * OLD + outOff + col] = v;
        Q[row * 1024 + col] = (_Float16)v;
      }
    }
  }
}

// ---------------- pos row norms -> out[row*3072 + 2048] ----------------------
__global__ __launch_bounds__(256) void pnorm(float* __restrict__ o) {
  const int row = blockIdx.x, t = threadIdx.x;
  const float4 v = *(const float4*)&o[(size_t)row * OLD + D + t * 4];
  float s = v.x * v.x + v.y * v.y + v.z * v.z + v.w * v.w;
#pragma unroll
  for (int off = 32; off; off >>= 1) s += __shfl_down(s, off, 64);
  __shared__ float wsum[4];
  if ((t & 63) == 0) wsum[t >> 6] = s;
  __syncthreads();
  if (t == 0) o[(size_t)row * OLD + 2048] = wsum[0] + wsum[1] + wsum[2] + wsum[3];
}

// ====== dist MFMA (single f16 pair) + fused per-row TOP-2 ===================
// 256x256 tile, 8 waves (2M x 4N), dbuf, 1 barrier/k-step, chunk XOR swizzle.
// Aq/Pq: f16 [4096][1024]. part: float4 (v1,j1,v2,j2) per block (16 blocks/row).
__global__ __launch_bounds__(512, 2) void dist_mfma(
    const _Float16* __restrict__ Aq, const _Float16* __restrict__ Pq,
    float* __restrict__ o) {
  __shared__ __align__(16) u16 lA[2][256 * 32];
  __shared__ __align__(16) u16 lB[2][256 * 32];
  __shared__ float sv1[256][4], sv2[256][4];
  __shared__ int sj1[256][4], sj2[256][4];
  const int tid = threadIdx.x, lane = tid & 63, wave = tid >> 6;
  const int waveM = wave >> 2, waveN = wave & 3;   // 2M x 4N
  const int row16 = lane & 15, quad = lane >> 4;
  const int Mbase = blockIdx.y * 256;
  const int Nbase = blockIdx.x * 256;
  f4v acc[8][4] = {};

  auto STAGE = [&](int buf, int kk) {
#pragma unroll
    for (int i = 0; i < 2; ++i) {
      const int c = i * 512 + tid;                  // 16B chunk id (0..1023)
      const int row = c >> 2;
      const int col8 = ((c & 3) ^ ((row >> 1) & 3)) * 8;  // slot swizzle
      u16* la = &lA[buf][(i * 512 + wave * 64) * 8];      // wave-uniform base
      u16* lb = &lB[buf][(i * 512 + wave * 64) * 8];
      gld16(&Aq[(size_t)(Mbase + row) * 1024 + kk + col8], la);
      gld16(&Pq[(size_t)(Nbase + row) * 1024 + kk + col8], lb);
    }
  };

  STAGE(0, 0);
  __syncthreads();                      // buf0 ready
  int cur = 0;
  const int slot = (quad ^ ((row16 >> 1) & 3)) * 8;   // read-side swizzle
  for (int t = 1; t <= 32; ++t) {
    if (t < 32) STAGE(cur ^ 1, t * 32); // prefetch next tile
    h8v a[8], b[4];
#pragma unroll
    for (int mi = 0; mi < 8; ++mi)
      a[mi] = *(const h8v*)&lA[cur][(waveM * 128 + mi * 16 + row16) * 32 + slot];
#pragma unroll
    for (int ni = 0; ni < 4; ++ni)
      b[ni] = *(const h8v*)&lB[cur][(waveN * 64 + ni * 16 + row16) * 32 + slot];
#pragma unroll
    for (int mi = 0; mi < 8; ++mi)
#pragma unroll
      for (int ni = 0; ni < 4; ++ni)
        acc[mi][ni] =
            __builtin_amdgcn_mfma_f32_16x16x32_f16(a[mi], b[ni], acc[mi][ni], 0, 0, 0);
    __syncthreads();                    // stages landed; safe to swap
    cur ^= 1;
  }

  // epilogue: d = p2[col] - 2*S; per-row TOP-2 across this block's 256 cols.
  float p2c[4];
#pragma unroll
  for (int ni = 0; ni < 4; ++ni)
    p2c[ni] = o[(size_t)(Nbase + waveN * 64 + ni * 16 + row16) * OLD + 2048];
#pragma unroll
  for (int mi = 0; mi < 8; ++mi)
#pragma unroll
    for (int r = 0; r < 4; ++r) {
      const int rg = Mbase + waveM * 128 + mi * 16 + quad * 4 + r;
      Top2 tp; tp.v1 = 3.0e38f; tp.v2 = 3.0e38f; tp.j1 = 0; tp.j2 = 1;
#pragma unroll
      for (int ni = 0; ni < 4; ++ni) {
        const int cg = Nbase + waveN * 64 + ni * 16 + row16;
        if (cg != rg) t2_insert(tp, p2c[ni] - 2.0f * acc[mi][ni][r], cg);
      }
#pragma unroll
      for (int m = 1; m < 16; m <<= 1) {  // across the 16 row16 lanes
        const float ov1 = __shfl_xor(tp.v1, m, 64);
        const int oj1 = __shfl_xor(tp.j1, m, 64);
        const float ov2 = __shfl_xor(tp.v2, m, 64);
        const int oj2 = __shfl_xor(tp.j2, m, 64);
        t2_insert(tp, ov1, oj1);
        t2_insert(tp, ov2, oj2);
      }
      if (row16 == 0) {
        const int rl = waveM * 128 + mi * 16 + quad * 4 + r;
        sv1[rl][waveN] = tp.v1; sj1[rl][waveN] = tp.j1;
        sv2[rl][waveN] = tp.v2; sj2[rl][waveN] = tp.j2;
      }
    }
  __syncthreads();
  if (tid < 256) {
    Top2 tp; tp.v1 = sv1[tid][0]; tp.j1 = sj1[tid][0];
    tp.v2 = sv2[tid][0]; tp.j2 = sj2[tid][0];
#pragma unroll
    for (int w = 1; w < 4; ++w) {
      t2_insert(tp, sv1[tid][w], sj1[tid][w]);
      t2_insert(tp, sv2[tid][w], sj2[tid][w]);
    }
    ((float4*)&o[(size_t)(Mbase + tid) * OLD + 2056])[blockIdx.x] =
        make_float4(tp.v1, __int_as_float(tp.j1), tp.v2, __int_as_float(tp.j2));
  }
}

// ===== final: global TOP-4, EXACT fp32 refine, gather neg row ================
__global__ __launch_bounds__(256) void argmin_refine(float* __restrict__ o) {
  const int i = blockIdx.x, t = threadIdx.x;
  __shared__ int gj[4];
  if (t < 64) {
    Top4 tp;
#pragma unroll
    for (int c = 0; c < 4; ++c) { tp.v[c] = 3.0e38f; tp.j[c] = 0; }
    if (t < 16) {   // 16 partial blocks (dist grid.x = 16)
      const float4 p = ((const float4*)&o[(size_t)i * OLD + 2056])[t];
      t4_insert(tp, p.x, __float_as_int(p.y));
      t4_insert(tp, p.z, __float_as_int(p.w));
    }
#pragma unroll
    for (int m = 1; m < 32; m <<= 1) {
#pragma unroll
      for (int c = 0; c < 4; ++c) {
        const float ov = __shfl_xor(tp.v[c], m, 64);
        const int oj = __shfl_xor(tp.j[c], m, 64);
        t4_insert(tp, ov, oj);
      }
    }
    if (t == 0) {
#pragma unroll
      for (int c = 0; c < 4; ++c)
        gj[c] = (tp.j[c] < 0) ? 0 : (tp.j[c] > B - 1 ? B - 1 : tp.j[c]);  // clamp
    }
  }
  __syncthreads();
  int jj[4];
#pragma unroll
  for (int c = 0; c < 4; ++c) jj[c] = gj[c];
  // exact fp32: d_c = |p_jc|^2 - 2 a_i.p_jc (norms recomputed locally)
  const float4 a4 = *(const float4*)&o[(size_t)i * OLD + t * 4];
  float s[4], n[4];
#pragma unroll
  for (int c = 0; c < 4; ++c) {
    const float4 q = *(const float4*)&o[(size_t)jj[c] * OLD + D + t * 4];
    s[c] = a4.x * q.x + a4.y * q.y + a4.z * q.z + a4.w * q.w;
    n[c] = q.x * q.x + q.y * q.y + q.z * q.z + q.w * q.w;
  }
#pragma unroll
  for (int off = 32; off; off >>= 1)
#pragma unroll
    for (int c = 0; c < 4; ++c) {
      s[c] += __shfl_down(s[c], off, 64);
      n[c] += __shfl_down(n[c], off, 64);
    }
  __shared__ float wsum[4][8];
  __shared__ int sjf;
  if ((t & 63) == 0)
#pragma unroll
    for (int c = 0; c < 4; ++c) {
      wsum[t >> 6][c] = s[c];
      wsum[t >> 6][4 + c] = n[c];
    }
  __syncthreads();
  if (t == 0) {
    float bd = 3.4e38f; int bj = 0x7fffffff;
#pragma unroll
    for (int c = 0; c < 4; ++c) {
      const float S = wsum[0][c] + wsum[1][c] + wsum[2][c] + wsum[3][c];
      const float N = wsum[0][4 + c] + wsum[1][4 + c] + wsum[2][4 + c] + wsum[3][4 + c];
      const float d = N - 2.0f * S;
      const int j = jj[c];
      if (d < bd || (d == bd && j < bj)) { bd = d; bj = j; }
    }
    sjf = bj;
  }
  __syncthreads();
  const int j = sjf;
  ((float4*)&o[(size_t)i * OLD + 2048])[t] = ((const float4*)&o[(size_t)j * OLD + D])[t];
}

// ================== round-4 fallback path (fp32 vector, ws-free) =============
__global__ __launch_bounds__(256) void enc_gemm(
    const float* __restrict__ X, const float* __restrict__ W,
    const float* __restrict__ bia, float* __restrict__ out, int outOff) {
  __shared__ float lA[32][LDK];
  __shared__ float lW[32][LDK];
  const int tid = threadIdx.x;
  const int Mbase = blockIdx.y * 64;
  const int Nbase = blockIdx.x * 64;
  const int ty = tid >> 4, tx = tid & 15;
  float acc[4][4] = {};
  for (int k0 = 0; k0 < D; k0 += 32) {
    __syncthreads();
#pragma unroll
    for (int h = 0; h < 2; ++h) {
      const int ch = tid + h * 256;
      const int r = ch >> 3, c4 = (ch & 7) * 4;
      const float4 a4 = *(const float4*)&X[(size_t)(Mbase + r) * D + k0 + c4];
      lA[c4 + 0][r] = a4.x; lA[c4 + 1][r] = a4.y;
      lA[c4 + 2][r] = a4.z; lA[c4 + 3][r] = a4.w;
      const int kr = ch >> 4, nc = (ch & 15) * 4;
      *(float4*)&lW[kr][nc] = *(const float4*)&W[(size_t)(k0 + kr) * D + Nbase + nc];
    }
    __syncthreads();
#pragma unroll
    for (int kk = 0; kk < 32; ++kk) {
      const float4 av = *(const float4*)&lA[kk][ty * 4];
      const float4 wv = *(const float4*)&lW[kk][tx * 4];
      acc[0][0] += av.x * wv.x; acc[0][1] += av.x * wv.y; acc[0][2] += av.x * wv.z; acc[0][3] += av.x * wv.w;
      acc[1][0] += av.y * wv.x; acc[1][1] += av.y * wv.y; acc[1][2] += av.y * wv.z; acc[1][3] += av.y * wv.w;
      acc[2][0] += av.z * wv.x; acc[2][1] += av.z * wv.y; acc[2][2] += av.z * wv.z; acc[2][3] += av.z * wv.w;
      acc[3][0] += av.w * wv.x; acc[3][1] += av.w * wv.y; acc[3][2] += av.w * wv.z; acc[3][3] += av.w * wv.w;
    }
  }
  const float4 b4 = *(const float4*)&bia[Nbase + tx * 4];
#pragma unroll
  for (int i = 0; i < 4; ++i) {
    const int row = Mbase + ty * 4 + i;
    float4 ov;
    ov.x = acc[i][0] + b4.x; ov.y = acc[i][1] + b4.y;
    ov.z = acc[i][2] + b4.z; ov.w = acc[i][3] + b4.w;
    *(float4*)&out[(size_t)row * OLD + outOff + Nbase + tx * 4] = ov;
  }
}

__global__ __launch_bounds__(256) void dist_argmin_f32(float* __restrict__ o) {
  __shared__ float lA[32][LDK];
  __shared__ float lB[32][LDK];
  const int tid = threadIdx.x;
  const int Mbase = blockIdx.y * 64, Nbase = blockIdx.x * 64;
  const int ty = tid >> 4, tx = tid & 15;
  float acc[4][4] = {};
  for (int k0 = 0; k0 < D; k0 += 32) {
    __syncthreads();
#pragma unroll
    for (int h = 0; h < 2; ++h) {
      const int ch = tid + h * 256;
      const int r = ch >> 3, c4 = (ch & 7) * 4;
      const float4 a4 = *(const float4*)&o[(size_t)(Mbase + r) * OLD + k0 + c4];
      const float4 b4 = *(const float4*)&o[(size_t)(Nbase + r) * OLD + D + k0 + c4];
      lA[c4 + 0][r] = a4.x; lA[c4 + 1][r] = a4.y;
      lA[c4 + 2][r] = a4.z; lA[c4 + 3][r] = a4.w;
      lB[c4 + 0][r] = b4.x; lB[c4 + 1][r] = b4.y;
      lB[c4 + 2][r] = b4.z; lB[c4 + 3][r] = b4.w;
    }
    __syncthreads();
#pragma unroll
    for (int kk = 0; kk < 32; ++kk) {
      const float4 av = *(const float4*)&lA[kk][ty * 4];
      const float4 bv = *(const float4*)&lB[kk][tx * 4];
      acc[0][0] += av.x * bv.x; acc[0][1] += av.x * bv.y; acc[0][2] += av.x * bv.z; acc[0][3] += av.x * bv.w;
      acc[1][0] += av.y * bv.x; acc[1][1] += av.y * bv.y; acc[1][2] += av.y * bv.z; acc[1][3] += av.y * bv.w;
      acc[2][0] += av.z * bv.x; acc[2][1] += av.z * bv.y; acc[2][2] += av.z * bv.z; acc[2][3] += av.z * bv.w;
      acc[3][0] += av.w * bv.x; acc[3][1] += av.w * bv.y; acc[3][2] += av.w * bv.z; acc[3][3] += av.w * bv.w;
    }
  }
  float colp2[4];
#pragma unroll
  for (int j = 0; j < 4; ++j)
    colp2[j] = o[(size_t)(Nbase + tx * 4 + j) * OLD + 2048];
#pragma unroll
  for (int i = 0; i < 4; ++i) {
    const int rg = Mbase + ty * 4 + i;
    float bv = 3.0e38f; int bj = 0;
#pragma unroll
    for (int j = 0; j < 4; ++j) {
      const int cg = Nbase + tx * 4 + j;
      const float d = colp2[j] - 2.0f * acc[i][j];
      if (cg != rg && d < bv) { bv = d; bj = cg; }
    }
#pragma unroll
    for (int m = 1; m < 16; m <<= 1) {
      const float ov = __shfl_xor(bv, m, 64);
      const int oj = __shfl_xor(bj, m, 64);
      if (ov < bv || (ov == bv && oj < bj)) { bv = ov; bj = oj; }
    }
    if (tx == 0)
      ((float2*)&o[(size_t)rg * OLD + 2056])[blockIdx.x] =
          make_float2(bv, __int_as_float(bj));
  }
}

__global__ __launch_bounds__(256) void argmin_final_f2(float* __restrict__ o, int nblk) {
  const int i = blockIdx.x, t = threadIdx.x;
  __shared__ int sj;
  if (t < 64) {
    float v = 3.4e38f; int j = 0x7fffffff;
    if (t < nblk) {
      const float2 p = ((const float2*)&o[(size_t)i * OLD + 2056])[t];
      v = p.x; j = __float_as_int(p.y);
    }
#pragma unroll
    for (int m = 32; m; m >>= 1) {
      const float ov = __shfl_xor(v, m, 64);
      const int oj = __shfl_xor(j, m, 64);
      if (ov < v || (ov == v && oj < j)) { v = ov; j = oj; }
    }
    if (t == 0) sj = (j < 0) ? 0 : (j > B - 1 ? B - 1 : j);
  }
  __syncthreads();
  const int j = sj;
  ((float4*)&o[(size_t)i * OLD + 2048])[t] = ((const float4*)&o[(size_t)j * OLD + D])[t];
}

extern "C" void kernel_launch(void* const* d_in, const int* in_sizes, int n_in,
                              void* d_out, int out_size, void* d_ws, size_t ws_size,
                              hipStream_t stream) {
  const float* anchor_x = (const float*)d_in[0];  // [4096,1024] f32
  const float* pos_x    = (const float*)d_in[1];  // [4096,1024] f32
  const float* W        = (const float*)d_in[2];  // [1024,1024] f32
  const float* b        = (const float*)d_in[3];  // [1024] f32
  float* out = (float*)d_out;                     // [4096,3072] f32
  char* ws = (char*)d_ws;
  const size_t MB = 1024 * 1024;

  if (ws_size >= 36 * MB) {  // fast path needs 36 MB
    _Float16* Aq = (_Float16*)(ws);            // [4096][1024] f16, 8 MB
    _Float16* Pq = (_Float16*)(ws + 8 * MB);   // 8 MB
    u16* WtQ     = (u16*)(ws + 16 * MB);       // [1024][2048] bf16 hi|mid, 4 MB
    u16* posXq   = (u16*)(ws + 20 * MB);       // [4096][2048] bf16 hi|mid, 16 MB
    splitT_W<<<dim3(32, 32), dim3(32, 8), 0, stream>>>(W, WtQ);
    splitX2<<<2 * B, 256, 0, stream>>>(anchor_x, pos_x, (u16*)out, posXq);
    enc_mfma<<<dim3(8, 64), 256, 0, stream>>>(out, posXq, WtQ, b, Aq, Pq);
    pnorm<<<B, 256, 0, stream>>>(out);
    dist_mfma<<<dim3(16, 16), 512, 0, stream>>>(Aq, Pq, out);
    argmin_refine<<<B, 256, 0, stream>>>(out);
  } else {  // round-4 proven path: d_ws untouched
    enc_gemm<<<dim3(16, 64), 256, 0, stream>>>(anchor_x, W, b, out, 0);
    enc_gemm<<<dim3(16, 64), 256, 0, stream>>>(pos_x,    W, b, out, 1024);
    pnorm<<<B, 256, 0, stream>>>(out);
    dist_argmin_f32<<<dim3(64, 64), 256, 0, stream>>>(out);
    argmin_final_f2<<<B, 256, 0, stream>>>(out, 64);
  }
}